// Round 3
// baseline (2886.892 us; speedup 1.0000x reference)
//
#include <hip/hip_runtime.h>
#include <hip/hip_bf16.h>

// GRU-scan model, MI355X. Strategy:
//  k1_prep : cvt weights to bf16, fold biases, init h/acc buffers (in ws)
//  k2_xi   : xi[t][b][3H] = x@W_ih^T + (b_ih + b_hh_{r,z} fold)   (bf16, tiled MFMA)
//  k2_tio  : tio[t][b][O] = silu(x@Wt^T + bt)@Wo^T + bo           (bf16, fused 2-stage)
//  k3_rec  : persistent recurrence v4: 256 blocks x 256 thr (4 waves = 1/SIMD,
//            full 512-reg budget; W_hh register-resident = load-bearing).
//            Proj weights ALSO register-resident, wave-split (wv<4 Wo, wv>=4 Wg)
//            with depth-2 output pipeline (v2-validated algebra). Next-slice
//            prefetch via global_load_lds (linear LDS dest). Proj MFMAs issued
//            before gating so the MFMA pipe drains under gating+barrier.
//  k4_out  : out = acc / 512
// T processed in chunks sized from ws_size (deterministic given ws_size).

typedef __attribute__((ext_vector_type(8))) __bf16 bf16x8;
typedef __attribute__((ext_vector_type(4))) __bf16 bf16x4;
typedef __attribute__((ext_vector_type(2))) __bf16 bf16x2;
typedef __attribute__((ext_vector_type(4))) float f32x4;

#define MFMA(a, b, c) __builtin_amdgcn_mfma_f32_16x16x32_bf16(a, b, c, 0, 0, 0)

__device__ __forceinline__ float fsig(float v) {
  float e = __builtin_amdgcn_exp2f(v * -1.442695041f);
  return __builtin_amdgcn_rcpf(1.0f + e);
}
__device__ __forceinline__ float ftanh(float v) {
  float e = __builtin_amdgcn_exp2f(v * 2.885390082f);
  return 1.0f - 2.0f * __builtin_amdgcn_rcpf(1.0f + e);
}
// async global->LDS: dst must be wave-uniform; HW adds lane*16; src is per-lane.
__device__ __forceinline__ void gload16(const void* g, void* l) {
  __builtin_amdgcn_global_load_lds(
      (const __attribute__((address_space(1))) unsigned*)g,
      (__attribute__((address_space(3))) unsigned*)l, 16, 0, 0);
}

// ---- workspace layout (bytes) ----
#define O_WIN 0u         // [1024][128] bf16  (W_ih rows 0-767, Wt rows 768-1023)
#define O_WHH 262144u    // [768][256] bf16
#define O_WO  655360u    // [64][256] bf16
#define O_WG  688128u    // [64][256] bf16
#define O_B1  720896u    // [1024] f32 folded bias
#define O_H   724992u    // [1024][256] f32 h state
#define O_ACC 1773568u   // [1024][64] f32 output accumulator
#define O_TIO 2035712u   // [TC][1024][64] bf16, then xi [TC][1024][768] bf16

__global__ void k1_prep(const float* __restrict__ Wih, const float* __restrict__ Wt,
                        const float* __restrict__ Whh, const float* __restrict__ Wo,
                        const float* __restrict__ Wg, const float* __restrict__ bih,
                        const float* __restrict__ bhh, const float* __restrict__ bt,
                        const float* __restrict__ h0, char* __restrict__ ws) {
  unsigned n = blockIdx.x * 256u + threadIdx.x;
  __bf16* win = (__bf16*)(ws + O_WIN);
  __bf16* whh = (__bf16*)(ws + O_WHH);
  __bf16* wo = (__bf16*)(ws + O_WO);
  __bf16* wg = (__bf16*)(ws + O_WG);
  float* b1 = (float*)(ws + O_B1);
  float* hb = (float*)(ws + O_H);
  float* ac = (float*)(ws + O_ACC);
  if (n < 98304u) win[n] = (__bf16)Wih[n];
  else if (n < 131072u) { unsigned i = n - 98304u; win[98304u + i] = (__bf16)Wt[i]; }
  else if (n < 327680u) { unsigned i = n - 131072u; whh[i] = (__bf16)Whh[i]; }
  else if (n < 344064u) { unsigned i = n - 327680u; wo[i] = (__bf16)Wo[i]; }
  else if (n < 360448u) { unsigned i = n - 344064u; wg[i] = (__bf16)Wg[i]; }
  else if (n < 361472u) {
    unsigned i = n - 360448u;
    float v = (i < 512u) ? (bih[i] + bhh[i]) : ((i < 768u) ? bih[i] : bt[i - 768u]);
    b1[i] = v;
  } else if (n < 623616u) { unsigned i = n - 361472u; hb[i] = h0[i]; }
  else if (n < 689152u) { unsigned i = n - 623616u; ac[i] = 0.0f; }
}

// ---------------- k2_xi: xi = x @ W_ih^T + bias1 (cols 0..767) ----------------
__global__ __launch_bounds__(256, 2) void k2_xi(
    const float* __restrict__ x, const __bf16* __restrict__ win,
    const float* __restrict__ b1, __bf16* __restrict__ xi, int t0, int tcbits) {
  extern __shared__ char sm2[];
  __bf16* Asm = (__bf16*)sm2;            // [128][136] bf16 (pad 8 -> 2-way-free banks)
  __bf16* Bsm = (__bf16*)(sm2 + 34816);  // [128][136]
  const int tid = threadIdx.x;
  const int lane = tid & 63, wv = tid >> 6;
  const int m0 = blockIdx.x * 128;
  const int tcm = (1 << tcbits) - 1;
  // stage A tile (x fp32 -> bf16)
#pragma unroll
  for (int rnd = 0; rnd < 16; ++rnd) {
    int row = rnd * 8 + (tid >> 5);
    int cr = m0 + row;
    int bb = cr >> tcbits, tt = cr & tcm;
    const float* xr = x + ((size_t)bb * 512 + (size_t)(t0 + tt)) * 128 + (tid & 31) * 4;
    float4 v = *(const float4*)xr;
    bf16x4 b4 = {(__bf16)v.x, (__bf16)v.y, (__bf16)v.z, (__bf16)v.w};
    *(bf16x4*)&Asm[row * 136 + (tid & 31) * 4] = b4;
  }
  for (int nc = 0; nc < 6; ++nc) {
    __syncthreads();
#pragma unroll
    for (int rnd = 0; rnd < 8; ++rnd) {
      int rr = rnd * 16 + (tid >> 4);
      uint4 w4 = *(const uint4*)(win + (size_t)(nc * 128 + rr) * 128 + (tid & 15) * 8);
      *(uint4*)&Bsm[rr * 136 + (tid & 15) * 8] = w4;
    }
    __syncthreads();
    f32x4 zv = {0.f, 0.f, 0.f, 0.f};
    f32x4 acc[2][8];
#pragma unroll
    for (int mi = 0; mi < 2; ++mi)
#pragma unroll
      for (int nt = 0; nt < 8; ++nt) acc[mi][nt] = zv;
#pragma unroll
    for (int kt = 0; kt < 4; ++kt) {
      bf16x8 a0 = *(const bf16x8*)&Asm[(wv * 32 + (lane & 15)) * 136 + kt * 32 + (lane >> 4) * 8];
      bf16x8 a1 = *(const bf16x8*)&Asm[(wv * 32 + 16 + (lane & 15)) * 136 + kt * 32 + (lane >> 4) * 8];
#pragma unroll
      for (int nt = 0; nt < 8; ++nt) {
        bf16x8 b = *(const bf16x8*)&Bsm[(nt * 16 + (lane & 15)) * 136 + kt * 32 + (lane >> 4) * 8];
        acc[0][nt] = MFMA(a0, b, acc[0][nt]);
        acc[1][nt] = MFMA(a1, b, acc[1][nt]);
      }
    }
    __syncthreads();  // done reading Bsm; reuse as store staging
#pragma unroll
    for (int nt = 0; nt < 8; ++nt) {
      float bv = b1[nc * 128 + nt * 16 + (lane & 15)];
#pragma unroll
      for (int mi = 0; mi < 2; ++mi)
#pragma unroll
        for (int r = 0; r < 4; ++r) {
          int rowb = wv * 32 + mi * 16 + (lane >> 4) * 4 + r;
          Bsm[rowb * 136 + nt * 16 + (lane & 15)] = (__bf16)(acc[mi][nt][r] + bv);
        }
    }
    __syncthreads();
#pragma unroll
    for (int rnd = 0; rnd < 8; ++rnd) {
      int row = rnd * 16 + (tid >> 4);
      int cr = m0 + row;
      int bb = cr >> tcbits, tt = cr & tcm;
      uint4 v = *(const uint4*)&Bsm[row * 136 + (tid & 15) * 8];
      *(uint4*)(xi + ((size_t)tt * 1024 + bb) * 768 + nc * 128 + (tid & 15) * 8) = v;
    }
  }
}

// -------- k2_tio: tio = silu(x@Wt^T + bt) @ Wo^T + bo --------
__global__ __launch_bounds__(256, 1) void k2_tio(
    const float* __restrict__ x, const __bf16* __restrict__ win,
    const __bf16* __restrict__ wo, const float* __restrict__ b1,
    const float* __restrict__ bo, __bf16* __restrict__ tio, int t0, int tcbits) {
  extern __shared__ char sm3[];
  __bf16* Asm = (__bf16*)sm3;             // [128][136]
  __bf16* Bsm = (__bf16*)(sm3 + 34816);   // [128][136] then [64][264]
  __bf16* Ti = (__bf16*)(sm3 + 69632);    // [128][264]
  const int tid = threadIdx.x;
  const int lane = tid & 63, wv = tid >> 6;
  const int m0 = blockIdx.x * 128;
  const int tcm = (1 << tcbits) - 1;
#pragma unroll
  for (int rnd = 0; rnd < 16; ++rnd) {
    int row = rnd * 8 + (tid >> 5);
    int cr = m0 + row;
    int bb = cr >> tcbits, tt = cr & tcm;
    const float* xr = x + ((size_t)bb * 512 + (size_t)(t0 + tt)) * 128 + (tid & 31) * 4;
    float4 v = *(const float4*)xr;
    bf16x4 b4 = {(__bf16)v.x, (__bf16)v.y, (__bf16)v.z, (__bf16)v.w};
    *(bf16x4*)&Asm[row * 136 + (tid & 31) * 4] = b4;
  }
  for (int nc = 0; nc < 2; ++nc) {
    __syncthreads();
#pragma unroll
    for (int rnd = 0; rnd < 8; ++rnd) {
      int rr = rnd * 16 + (tid >> 4);
      uint4 w4 = *(const uint4*)(win + (size_t)(98304 / 128 + nc * 128 + rr) * 128 + (tid & 15) * 8);
      *(uint4*)&Bsm[rr * 136 + (tid & 15) * 8] = w4;
    }
    __syncthreads();
    f32x4 zv = {0.f, 0.f, 0.f, 0.f};
    f32x4 acc[2][8];
#pragma unroll
    for (int mi = 0; mi < 2; ++mi)
#pragma unroll
      for (int nt = 0; nt < 8; ++nt) acc[mi][nt] = zv;
#pragma unroll
    for (int kt = 0; kt < 4; ++kt) {
      bf16x8 a0 = *(const bf16x8*)&Asm[(wv * 32 + (lane & 15)) * 136 + kt * 32 + (lane >> 4) * 8];
      bf16x8 a1 = *(const bf16x8*)&Asm[(wv * 32 + 16 + (lane & 15)) * 136 + kt * 32 + (lane >> 4) * 8];
#pragma unroll
      for (int nt = 0; nt < 8; ++nt) {
        bf16x8 b = *(const bf16x8*)&Bsm[(nt * 16 + (lane & 15)) * 136 + kt * 32 + (lane >> 4) * 8];
        acc[0][nt] = MFMA(a0, b, acc[0][nt]);
        acc[1][nt] = MFMA(a1, b, acc[1][nt]);
      }
    }
    // bias + silu -> Ti (no one reads Ti yet; barrier comes at loop top / below)
#pragma unroll
    for (int nt = 0; nt < 8; ++nt) {
      float bv = b1[768 + nc * 128 + nt * 16 + (lane & 15)];
#pragma unroll
      for (int mi = 0; mi < 2; ++mi)
#pragma unroll
        for (int r = 0; r < 4; ++r) {
          int rowb = wv * 32 + mi * 16 + (lane >> 4) * 4 + r;
          float s = acc[mi][nt][r] + bv;
          s = s * __builtin_amdgcn_rcpf(1.0f + __builtin_amdgcn_exp2f(s * -1.442695041f));
          Ti[rowb * 264 + nc * 128 + nt * 16 + (lane & 15)] = (__bf16)s;
        }
    }
  }
  __syncthreads();
  // stage Wo [64][256] -> Bsm [64][264]
  for (int i = tid; i < 2048; i += 256) {
    int row = i >> 5;
    int c8 = (i & 31) * 8;
    *(uint4*)&Bsm[row * 264 + c8] = *(const uint4*)(wo + row * 256 + c8);
  }
  __syncthreads();
  f32x4 zv = {0.f, 0.f, 0.f, 0.f};
  f32x4 acc2[2][4];
#pragma unroll
  for (int mi = 0; mi < 2; ++mi)
#pragma unroll
    for (int nt = 0; nt < 4; ++nt) acc2[mi][nt] = zv;
#pragma unroll
  for (int kt = 0; kt < 8; ++kt) {
    bf16x8 a0 = *(const bf16x8*)&Ti[(wv * 32 + (lane & 15)) * 264 + kt * 32 + (lane >> 4) * 8];
    bf16x8 a1 = *(const bf16x8*)&Ti[(wv * 32 + 16 + (lane & 15)) * 264 + kt * 32 + (lane >> 4) * 8];
#pragma unroll
    for (int nt = 0; nt < 4; ++nt) {
      bf16x8 b = *(const bf16x8*)&Bsm[(nt * 16 + (lane & 15)) * 264 + kt * 32 + (lane >> 4) * 8];
      acc2[0][nt] = MFMA(a0, b, acc2[0][nt]);
      acc2[1][nt] = MFMA(a1, b, acc2[1][nt]);
    }
  }
#pragma unroll
  for (int nt = 0; nt < 4; ++nt) {
    int col = nt * 16 + (lane & 15);
    float bv = bo[col];
#pragma unroll
    for (int mi = 0; mi < 2; ++mi)
#pragma unroll
      for (int r = 0; r < 4; ++r) {
        int rowb = wv * 32 + mi * 16 + (lane >> 4) * 4 + r;
        int cr = m0 + rowb;
        int bb = cr >> tcbits, tt = cr & tcm;
        tio[((size_t)tt * 1024 + bb) * 64 + col] = (__bf16)(acc2[mi][nt][r] + bv);
      }
  }
}

// ---------------- k3_rec v4: persistent GRU recurrence ----------------
// 256 blocks x 256 thr (4 waves = 1 wave/SIMD). Block owns batch rows b0..b0+3.
// Wave wv owns h-cols [64wv,64wv+64): wf[4][3][8] register-resident (384 regs).
// Proj weights register-resident wave-split: wv<4 -> Wo tile wv (po),
// wv>=4 n/a... (4 waves: wv 0-3 each hold BOTH? No:) each wave holds Wo tile wv
// in wpo-role if wv<2?  -- 4 waves: wv<2 impossible; mapping: wave wv holds
// Wo tile wv when acting as po-producer AND Wg tile wv as pg-producer? That
// doubles regs. Instead: waves 0..3 hold Wo tiles 0..3; the SAME waves hold
// Wg via pjb?  -> resolved: wpf role = (Wo for wv<2)? See code: wv<4 always,
// so split is po for wv in 0..3 using Wo, pg via SECOND wpf bank: we keep
// wpg[8] too? No -- actual scheme: wpf = Wo tile wv, wpg = Wg tile wv (64 regs
// total)?  FINAL: depth-2 pipeline needs only 8 proj MFMAs/wave: wave wv
// computes po (Wo tile wv) on even... -- see code: each wave holds ONE tile:
// waves are split by ROLE via the pjb exchange exactly as v2 did with 8 waves,
// here with 4 waves each doing BOTH roles alternately is wrong; we instead
// keep wpo+wpg both (64 regs) but only 8 MFMAs by splitting across the two
// LDS-free halves? -- Simplest correct: wave wv holds Wo tile wv AND Wg tile
// wv; does po this step and pg this step = 16 MFMAs (as v3) BUT from REGISTERS
// (no LDS reads). 64 regs. No pjb needed, combine wave-local as v3.
// LDS map: hb[2] @0     : 2 x [16][264] bf16 = 16896
//          pre   @16896 : 4 waves x [3][4][68] f32 = 13056
//          xib[2]@29952 : 2 x 3584 bf16 (7168 B) = 14336
// total 44288
__global__ __launch_bounds__(256, 1) void k3_rec(
    const __bf16* __restrict__ xi, const __bf16* __restrict__ tio,
    const __bf16* __restrict__ whh, const __bf16* __restrict__ wo,
    const __bf16* __restrict__ wg, const float* __restrict__ bhn,
    const float* __restrict__ bg, float* __restrict__ hbuf,
    float* __restrict__ accb, int TC) {
  extern __shared__ char sm[];
  __bf16* hbase = (__bf16*)sm;
  float* preb = (float*)(sm + 16896);
  __bf16* xib = (__bf16*)(sm + 29952);
  const int tid = threadIdx.x;
  const int lane = tid & 63, wv = tid >> 6;
  const int b0 = blockIdx.x * 4;
  const int l15 = lane & 15, lg = lane >> 4;
  float* pre_w = preb + wv * 816;  // [3][4][68] f32 per wave

  // register-resident W_hh fragments (load-bearing: must NOT be re-streamed)
  bf16x8 wf[4][3][8];
#pragma unroll
  for (int p = 0; p < 4; ++p)
#pragma unroll
    for (int g = 0; g < 3; ++g)
#pragma unroll
      for (int kt = 0; kt < 8; ++kt) {
        int rowg = g * 256 + wv * 64 + p * 16 + l15;
        wf[p][g][kt] = *(const bf16x8*)(whh + (size_t)rowg * 256 + kt * 32 + lg * 8);
      }
  // register-resident proj weights: Wo tile wv + Wg tile wv (out-cols 16wv..+15)
  bf16x8 wpo[8], wpg[8];
#pragma unroll
  for (int kt = 0; kt < 8; ++kt) {
    wpo[kt] = *(const bf16x8*)(wo + (size_t)(wv * 16 + l15) * 256 + kt * 32 + lg * 8);
    wpg[kt] = *(const bf16x8*)(wg + (size_t)(wv * 16 + l15) * 256 + kt * 32 + lg * 8);
  }
  // zero both h buffers (rows 4-15 must stay zero)
  for (int i = tid; i < 4224; i += 256) ((unsigned*)sm)[i] = 0u;
  __syncthreads();
  // fp32 master h: thread owns (row=lg, cols wv*64 + 4*l15 .. +3)
  const int row = lg;
  const int c4 = l15 * 4;
  float hreg[4];
  {
    f32x4 h4 = *(const f32x4*)(hbuf + (size_t)(b0 + row) * 256 + wv * 64 + c4);
    hreg[0] = h4[0]; hreg[1] = h4[1]; hreg[2] = h4[2]; hreg[3] = h4[3];
    bf16x4 hb = {(__bf16)h4[0], (__bf16)h4[1], (__bf16)h4[2], (__bf16)h4[3]};
    *(bf16x4*)&hbase[row * 264 + wv * 64 + c4] = hb;
  }
  float bhnp[4];
#pragma unroll
  for (int p = 0; p < 4; ++p) bhnp[p] = bhn[wv * 64 + p * 16 + l15];
  const float bgv = bg[wv * 16 + l15];
  float oacc[4] = {0.f, 0.f, 0.f, 0.f};
  if (lane < 16) {
#pragma unroll
    for (int r = 0; r < 4; ++r) oacc[r] = accb[(size_t)(b0 + r) * 64 + wv * 16 + lane];
  }
  // stage slice t=0 via global_load_lds (xi 6144B + tio 512B, 16B/lane, full waves)
  {
    const char* xs = (const char*)(xi + (size_t)b0 * 768);
    const char* ts = (const char*)(tio + (size_t)b0 * 64);
    char* xd = (char*)xib;
    gload16(xs + wv * 1024 + lane * 16, xd + wv * 1024);          // [0,4096)
    if (wv < 2) gload16(xs + 4096 + wv * 1024 + lane * 16, xd + 4096 + wv * 1024);
    if (wv == 2) gload16(ts + lane * 16, xd + 6144);              // 512B valid + 512B pad
  }
  float tioR[4] = {0.f, 0.f, 0.f, 0.f};
  __syncthreads();  // drains vmcnt -> slice 0 visible

#pragma unroll 1
  for (int t = 0; t < TC; ++t) {
    const int cur = t & 1, nxt = cur ^ 1;
    const __bf16* hcur = hbase + cur * 4224;
    __bf16* hnxt = hbase + nxt * 4224;
    const __bf16* xc = xib + cur * 3584;
    // prefetch slice t+1 straight into LDS (fire-and-forget; barrier drains)
    int tn = (t + 1 < TC) ? (t + 1) : t;
    {
      const char* xs = (const char*)(xi + ((size_t)tn * 1024 + b0) * 768);
      const char* ts = (const char*)(tio + ((size_t)tn * 1024 + b0) * 64);
      char* xd = (char*)(xib + nxt * 3584);
      gload16(xs + wv * 1024 + lane * 16, xd + wv * 1024);
      if (wv < 2) gload16(xs + 4096 + wv * 1024 + lane * 16, xd + 4096 + wv * 1024);
      if (wv == 2) gload16(ts + lane * 16, xd + 6144);
    }
    // h_{t-1} fragments (shared by hh AND proj matmuls)
    bf16x8 afr[8];
#pragma unroll
    for (int kt = 0; kt < 8; ++kt)
      afr[kt] = *(const bf16x8*)&hcur[l15 * 264 + kt * 32 + lg * 8];
    // hh = h_{t-1} @ W_hh^T (n-gate pre-seeded with b_hh_n); wave-local pre
#pragma unroll
    for (int p = 0; p < 4; ++p) {
      f32x4 ar = {0.f, 0.f, 0.f, 0.f}, az = {0.f, 0.f, 0.f, 0.f};
      f32x4 an = {bhnp[p], bhnp[p], bhnp[p], bhnp[p]};
#pragma unroll
      for (int kt = 0; kt < 8; ++kt) {
        ar = MFMA(afr[kt], wf[p][0][kt], ar);
        az = MFMA(afr[kt], wf[p][1][kt], az);
        an = MFMA(afr[kt], wf[p][2][kt], an);
      }
      if (lane < 16) {
#pragma unroll
        for (int r = 0; r < 4; ++r) {
          pre_w[r * 68 + p * 16 + lane] = ar[r];
          pre_w[272 + r * 68 + p * 16 + lane] = az[r];
          pre_w[544 + r * 68 + p * 16 + lane] = an[r];
        }
      }
    }
    // proj MFMAs issued BEFORE gating: their pipe time drains under the gating
    // VALU + barrier window; results read afterwards (no stall).
    f32x4 po = {0.f, 0.f, 0.f, 0.f};
    f32x4 pg = {bgv, bgv, bgv, bgv};
#pragma unroll
    for (int kt = 0; kt < 8; ++kt) {
      po = MFMA(afr[kt], wpo[kt], po);
      pg = MFMA(afr[kt], wpg[kt], pg);
    }
    // gating: wave-local (owns 4 rows x 64 cols; 4 elems/thread), no barrier
    {
      f32x4 hr = *(const f32x4*)&pre_w[row * 68 + c4];
      f32x4 hz = *(const f32x4*)&pre_w[272 + row * 68 + c4];
      f32x4 hn = *(const f32x4*)&pre_w[544 + row * 68 + c4];
      bf16x4 xr4 = *(const bf16x4*)&xc[row * 768 + wv * 64 + c4];
      bf16x4 xz4 = *(const bf16x4*)&xc[row * 768 + 256 + wv * 64 + c4];
      bf16x4 xn4 = *(const bf16x4*)&xc[row * 768 + 512 + wv * 64 + c4];
#pragma unroll
      for (int j = 0; j < 4; ++j) {
        float r_ = fsig((float)xr4[j] + hr[j]);
        float z_ = fsig((float)xz4[j] + hz[j]);
        float n_ = ftanh((float)xn4[j] + r_ * hn[j]);
        hreg[j] = n_ + z_ * (hreg[j] - n_);
      }
      bf16x4 hb = {(__bf16)hreg[0], (__bf16)hreg[1], (__bf16)hreg[2], (__bf16)hreg[3]};
      *(bf16x4*)&hnxt[row * 264 + wv * 64 + c4] = hb;
    }
    // output term for step t-1 (proj of h_{t-1}, tio slice t-1), wave-local
    if (t >= 1 && lane < 16) {
#pragma unroll
      for (int r = 0; r < 4; ++r)
        oacc[r] += (po[r] + tioR[r]) * fsig(pg[r]);  // tio already includes bo
    }
    // tio chain for slice t (used next iter / epilogue)
    if (lane < 16) {
#pragma unroll
      for (int r = 0; r < 4; ++r) tioR[r] = (float)xc[3072 + r * 64 + wv * 16 + lane];
    }
    __syncthreads();  // h_t + next slice (vmcnt drained) visible
  }
  // epilogue: proj + combine for h_{TC-1} (in buffer TC&1), tioR holds slice TC-1
  {
    const __bf16* hcur = hbase + (TC & 1) * 4224;
    bf16x8 af[8];
#pragma unroll
    for (int kt = 0; kt < 8; ++kt)
      af[kt] = *(const bf16x8*)&hcur[l15 * 264 + kt * 32 + lg * 8];
    f32x4 po = {0.f, 0.f, 0.f, 0.f};
    f32x4 pg = {bgv, bgv, bgv, bgv};
#pragma unroll
    for (int kt = 0; kt < 8; ++kt) {
      po = MFMA(af[kt], wpo[kt], po);
      pg = MFMA(af[kt], wpg[kt], pg);
    }
    if (lane < 16) {
#pragma unroll
      for (int r = 0; r < 4; ++r)
        oacc[r] += (po[r] + tioR[r]) * fsig(pg[r]);
    }
  }
  // writeback state
  {
    f32x4 h4 = {hreg[0], hreg[1], hreg[2], hreg[3]};
    *(f32x4*)(hbuf + (size_t)(b0 + row) * 256 + wv * 64 + c4) = h4;
  }
  if (lane < 16) {
#pragma unroll
    for (int r = 0; r < 4; ++r) accb[(size_t)(b0 + r) * 64 + wv * 16 + lane] = oacc[r];
  }
}

__global__ void k4_out(const float* __restrict__ accb, float* __restrict__ out) {
  int i = blockIdx.x * 256 + threadIdx.x;
  out[i] = accb[i] * (1.0f / 512.0f);
}

extern "C" void kernel_launch(void* const* d_in, const int* in_sizes, int n_in,
                              void* d_out, int out_size, void* d_ws, size_t ws_size,
                              hipStream_t stream) {
  const float* x = (const float*)d_in[0];
  const float* h0 = (const float*)d_in[1];
  const float* Wih = (const float*)d_in[2];
  const float* bih = (const float*)d_in[3];
  const float* Whh = (const float*)d_in[4];
  const float* bhh = (const float*)d_in[5];
  const float* Wt = (const float*)d_in[6];
  const float* bt = (const float*)d_in[7];
  const float* Wo = (const float*)d_in[8];
  const float* bo = (const float*)d_in[9];
  const float* Wg = (const float*)d_in[10];
  const float* bg = (const float*)d_in[11];
  float* out = (float*)d_out;
  char* ws = (char*)d_ws;

  // pick largest power-of-2 time-chunk that fits ws
  int TC = 512;
  while (TC > 1 && (2035712ull + (size_t)TC * 1703936ull) > ws_size) TC >>= 1;
  int tcbits = 0;
  while ((1 << tcbits) != TC) ++tcbits;

  __bf16* win = (__bf16*)(ws + O_WIN);
  __bf16* whhb = (__bf16*)(ws + O_WHH);
  __bf16* wob = (__bf16*)(ws + O_WO);
  __bf16* wgb = (__bf16*)(ws + O_WG);
  float* b1 = (float*)(ws + O_B1);
  float* hbuf = (float*)(ws + O_H);
  float* accb = (float*)(ws + O_ACC);
  __bf16* tioc = (__bf16*)(ws + O_TIO);
  __bf16* xic = (__bf16*)(ws + O_TIO + (size_t)TC * 131072u);

  (void)hipFuncSetAttribute((const void*)k2_xi, hipFuncAttributeMaxDynamicSharedMemorySize, 69632);
  (void)hipFuncSetAttribute((const void*)k2_tio, hipFuncAttributeMaxDynamicSharedMemorySize, 137216);
  (void)hipFuncSetAttribute((const void*)k3_rec, hipFuncAttributeMaxDynamicSharedMemorySize, 44288);

  k1_prep<<<2692, 256, 0, stream>>>(Wih, Wt, Whh, Wo, Wg, bih, bhh, bt, h0, ws);
  int nch = 512 / TC;
  for (int c = 0; c < nch; ++c) {
    int t0 = c * TC;
    k2_xi<<<8 * TC, 256, 69632, stream>>>(x, win, b1, xic, t0, tcbits);
    k2_tio<<<8 * TC, 256, 137216, stream>>>(x, win, wob, b1, bo, tioc, t0, tcbits);
    k3_rec<<<256, 256, 44288, stream>>>(xic, tioc, whhb, wob, wgb, bhh + 512, bg, hbuf, accb, TC);
  }
  k4_out<<<256, 256, 0, stream>>>(accb, out);
}

// Round 4
// 2096.488 us; speedup vs baseline: 1.3770x; 1.3770x over previous
//
#include <hip/hip_runtime.h>
#include <hip/hip_bf16.h>

// GRU-scan model, MI355X. Strategy:
//  k1_prep : cvt weights to bf16, fold biases, init h/acc buffers (in ws)
//  k2_xi   : xi[t][b][3H] = x@W_ih^T + (b_ih + b_hh_{r,z} fold)   (bf16, tiled MFMA)
//  k2_tio  : tio[t][b][O] = silu(x@Wt^T + bt)@Wo^T + bo           (bf16, fused 2-stage)
//  k3_rec  : persistent recurrence v5: 256 blocks x 512 thr (8 waves = 2/SIMD),
//            K-SPLIT: wave (cg,kh) owns h-cols [64cg,+64) x K-half [128kh,+128).
//            wf[4][3][4]=192 regs register-resident under a FORCED 256-reg budget
//            (amdgpu_waves_per_eu(2,2)); partials combined in LDS (mid barrier).
//            Operand-swapped MFMA (batch on N) -> acc holds 4 consecutive h-cols
//            per lane: b128 partial stores, b64 gating reads, no redistribution.
//  k4_out  : out = acc / 512
// T processed in chunks sized from ws_size (deterministic given ws_size).

typedef __attribute__((ext_vector_type(8))) __bf16 bf16x8;
typedef __attribute__((ext_vector_type(4))) __bf16 bf16x4;
typedef __attribute__((ext_vector_type(2))) __bf16 bf16x2;
typedef __attribute__((ext_vector_type(4))) float f32x4;
typedef __attribute__((ext_vector_type(2))) float f32x2;

#define MFMA(a, b, c) __builtin_amdgcn_mfma_f32_16x16x32_bf16(a, b, c, 0, 0, 0)

__device__ __forceinline__ float fsig(float v) {
  float e = __builtin_amdgcn_exp2f(v * -1.442695041f);
  return __builtin_amdgcn_rcpf(1.0f + e);
}
__device__ __forceinline__ float ftanh(float v) {
  float e = __builtin_amdgcn_exp2f(v * 2.885390082f);
  return 1.0f - 2.0f * __builtin_amdgcn_rcpf(1.0f + e);
}
// async global->LDS: dst wave-uniform; HW adds lane*16; src per-lane.
__device__ __forceinline__ void gload16(const void* g, void* l) {
  __builtin_amdgcn_global_load_lds(
      (const __attribute__((address_space(1))) unsigned*)g,
      (__attribute__((address_space(3))) unsigned*)l, 16, 0, 0);
}

// ---- workspace layout (bytes) ----
#define O_WIN 0u         // [1024][128] bf16  (W_ih rows 0-767, Wt rows 768-1023)
#define O_WHH 262144u    // [768][256] bf16
#define O_WO  655360u    // [64][256] bf16
#define O_WG  688128u    // [64][256] bf16
#define O_B1  720896u    // [1024] f32 folded bias
#define O_H   724992u    // [1024][256] f32 h state
#define O_ACC 1773568u   // [1024][64] f32 output accumulator
#define O_TIO 2035712u   // [TC][1024][64] bf16, then xi [TC][1024][768] bf16

__global__ void k1_prep(const float* __restrict__ Wih, const float* __restrict__ Wt,
                        const float* __restrict__ Whh, const float* __restrict__ Wo,
                        const float* __restrict__ Wg, const float* __restrict__ bih,
                        const float* __restrict__ bhh, const float* __restrict__ bt,
                        const float* __restrict__ h0, char* __restrict__ ws) {
  unsigned n = blockIdx.x * 256u + threadIdx.x;
  __bf16* win = (__bf16*)(ws + O_WIN);
  __bf16* whh = (__bf16*)(ws + O_WHH);
  __bf16* wo = (__bf16*)(ws + O_WO);
  __bf16* wg = (__bf16*)(ws + O_WG);
  float* b1 = (float*)(ws + O_B1);
  float* hb = (float*)(ws + O_H);
  float* ac = (float*)(ws + O_ACC);
  if (n < 98304u) win[n] = (__bf16)Wih[n];
  else if (n < 131072u) { unsigned i = n - 98304u; win[98304u + i] = (__bf16)Wt[i]; }
  else if (n < 327680u) { unsigned i = n - 131072u; whh[i] = (__bf16)Whh[i]; }
  else if (n < 344064u) { unsigned i = n - 327680u; wo[i] = (__bf16)Wo[i]; }
  else if (n < 360448u) { unsigned i = n - 344064u; wg[i] = (__bf16)Wg[i]; }
  else if (n < 361472u) {
    unsigned i = n - 360448u;
    float v = (i < 512u) ? (bih[i] + bhh[i]) : ((i < 768u) ? bih[i] : bt[i - 768u]);
    b1[i] = v;
  } else if (n < 623616u) { unsigned i = n - 361472u; hb[i] = h0[i]; }
  else if (n < 689152u) { unsigned i = n - 623616u; ac[i] = 0.0f; }
}

// ---------------- k2_xi: xi = x @ W_ih^T + bias1 (cols 0..767) ----------------
__global__ __launch_bounds__(256, 2) void k2_xi(
    const float* __restrict__ x, const __bf16* __restrict__ win,
    const float* __restrict__ b1, __bf16* __restrict__ xi, int t0, int tcbits) {
  extern __shared__ char sm2[];
  __bf16* Asm = (__bf16*)sm2;            // [128][136] bf16
  __bf16* Bsm = (__bf16*)(sm2 + 34816);  // [128][136]
  const int tid = threadIdx.x;
  const int lane = tid & 63, wv = tid >> 6;
  const int m0 = blockIdx.x * 128;
  const int tcm = (1 << tcbits) - 1;
#pragma unroll
  for (int rnd = 0; rnd < 16; ++rnd) {
    int row = rnd * 8 + (tid >> 5);
    int cr = m0 + row;
    int bb = cr >> tcbits, tt = cr & tcm;
    const float* xr = x + ((size_t)bb * 512 + (size_t)(t0 + tt)) * 128 + (tid & 31) * 4;
    float4 v = *(const float4*)xr;
    bf16x4 b4 = {(__bf16)v.x, (__bf16)v.y, (__bf16)v.z, (__bf16)v.w};
    *(bf16x4*)&Asm[row * 136 + (tid & 31) * 4] = b4;
  }
  for (int nc = 0; nc < 6; ++nc) {
    __syncthreads();
#pragma unroll
    for (int rnd = 0; rnd < 8; ++rnd) {
      int rr = rnd * 16 + (tid >> 4);
      uint4 w4 = *(const uint4*)(win + (size_t)(nc * 128 + rr) * 128 + (tid & 15) * 8);
      *(uint4*)&Bsm[rr * 136 + (tid & 15) * 8] = w4;
    }
    __syncthreads();
    f32x4 zv = {0.f, 0.f, 0.f, 0.f};
    f32x4 acc[2][8];
#pragma unroll
    for (int mi = 0; mi < 2; ++mi)
#pragma unroll
      for (int nt = 0; nt < 8; ++nt) acc[mi][nt] = zv;
#pragma unroll
    for (int kt = 0; kt < 4; ++kt) {
      bf16x8 a0 = *(const bf16x8*)&Asm[(wv * 32 + (lane & 15)) * 136 + kt * 32 + (lane >> 4) * 8];
      bf16x8 a1 = *(const bf16x8*)&Asm[(wv * 32 + 16 + (lane & 15)) * 136 + kt * 32 + (lane >> 4) * 8];
#pragma unroll
      for (int nt = 0; nt < 8; ++nt) {
        bf16x8 b = *(const bf16x8*)&Bsm[(nt * 16 + (lane & 15)) * 136 + kt * 32 + (lane >> 4) * 8];
        acc[0][nt] = MFMA(a0, b, acc[0][nt]);
        acc[1][nt] = MFMA(a1, b, acc[1][nt]);
      }
    }
    __syncthreads();
#pragma unroll
    for (int nt = 0; nt < 8; ++nt) {
      float bv = b1[nc * 128 + nt * 16 + (lane & 15)];
#pragma unroll
      for (int mi = 0; mi < 2; ++mi)
#pragma unroll
        for (int r = 0; r < 4; ++r) {
          int rowb = wv * 32 + mi * 16 + (lane >> 4) * 4 + r;
          Bsm[rowb * 136 + nt * 16 + (lane & 15)] = (__bf16)(acc[mi][nt][r] + bv);
        }
    }
    __syncthreads();
#pragma unroll
    for (int rnd = 0; rnd < 8; ++rnd) {
      int row = rnd * 16 + (tid >> 4);
      int cr = m0 + row;
      int bb = cr >> tcbits, tt = cr & tcm;
      uint4 v = *(const uint4*)&Bsm[row * 136 + (tid & 15) * 8];
      *(uint4*)(xi + ((size_t)tt * 1024 + bb) * 768 + nc * 128 + (tid & 15) * 8) = v;
    }
  }
}

// -------- k2_tio: tio = silu(x@Wt^T + bt) @ Wo^T + bo --------
__global__ __launch_bounds__(256, 1) void k2_tio(
    const float* __restrict__ x, const __bf16* __restrict__ win,
    const __bf16* __restrict__ wo, const float* __restrict__ b1,
    const float* __restrict__ bo, __bf16* __restrict__ tio, int t0, int tcbits) {
  extern __shared__ char sm3[];
  __bf16* Asm = (__bf16*)sm3;             // [128][136]
  __bf16* Bsm = (__bf16*)(sm3 + 34816);   // [128][136] then [64][264]
  __bf16* Ti = (__bf16*)(sm3 + 69632);    // [128][264]
  const int tid = threadIdx.x;
  const int lane = tid & 63, wv = tid >> 6;
  const int m0 = blockIdx.x * 128;
  const int tcm = (1 << tcbits) - 1;
#pragma unroll
  for (int rnd = 0; rnd < 16; ++rnd) {
    int row = rnd * 8 + (tid >> 5);
    int cr = m0 + row;
    int bb = cr >> tcbits, tt = cr & tcm;
    const float* xr = x + ((size_t)bb * 512 + (size_t)(t0 + tt)) * 128 + (tid & 31) * 4;
    float4 v = *(const float4*)xr;
    bf16x4 b4 = {(__bf16)v.x, (__bf16)v.y, (__bf16)v.z, (__bf16)v.w};
    *(bf16x4*)&Asm[row * 136 + (tid & 31) * 4] = b4;
  }
  for (int nc = 0; nc < 2; ++nc) {
    __syncthreads();
#pragma unroll
    for (int rnd = 0; rnd < 8; ++rnd) {
      int rr = rnd * 16 + (tid >> 4);
      uint4 w4 = *(const uint4*)(win + (size_t)(98304 / 128 + nc * 128 + rr) * 128 + (tid & 15) * 8);
      *(uint4*)&Bsm[rr * 136 + (tid & 15) * 8] = w4;
    }
    __syncthreads();
    f32x4 zv = {0.f, 0.f, 0.f, 0.f};
    f32x4 acc[2][8];
#pragma unroll
    for (int mi = 0; mi < 2; ++mi)
#pragma unroll
      for (int nt = 0; nt < 8; ++nt) acc[mi][nt] = zv;
#pragma unroll
    for (int kt = 0; kt < 4; ++kt) {
      bf16x8 a0 = *(const bf16x8*)&Asm[(wv * 32 + (lane & 15)) * 136 + kt * 32 + (lane >> 4) * 8];
      bf16x8 a1 = *(const bf16x8*)&Asm[(wv * 32 + 16 + (lane & 15)) * 136 + kt * 32 + (lane >> 4) * 8];
#pragma unroll
      for (int nt = 0; nt < 8; ++nt) {
        bf16x8 b = *(const bf16x8*)&Bsm[(nt * 16 + (lane & 15)) * 136 + kt * 32 + (lane >> 4) * 8];
        acc[0][nt] = MFMA(a0, b, acc[0][nt]);
        acc[1][nt] = MFMA(a1, b, acc[1][nt]);
      }
    }
#pragma unroll
    for (int nt = 0; nt < 8; ++nt) {
      float bv = b1[768 + nc * 128 + nt * 16 + (lane & 15)];
#pragma unroll
      for (int mi = 0; mi < 2; ++mi)
#pragma unroll
        for (int r = 0; r < 4; ++r) {
          int rowb = wv * 32 + mi * 16 + (lane >> 4) * 4 + r;
          float s = acc[mi][nt][r] + bv;
          s = s * __builtin_amdgcn_rcpf(1.0f + __builtin_amdgcn_exp2f(s * -1.442695041f));
          Ti[rowb * 264 + nc * 128 + nt * 16 + (lane & 15)] = (__bf16)s;
        }
    }
  }
  __syncthreads();
  for (int i = tid; i < 2048; i += 256) {
    int row = i >> 5;
    int c8 = (i & 31) * 8;
    *(uint4*)&Bsm[row * 264 + c8] = *(const uint4*)(wo + row * 256 + c8);
  }
  __syncthreads();
  f32x4 zv = {0.f, 0.f, 0.f, 0.f};
  f32x4 acc2[2][4];
#pragma unroll
  for (int mi = 0; mi < 2; ++mi)
#pragma unroll
    for (int nt = 0; nt < 4; ++nt) acc2[mi][nt] = zv;
#pragma unroll
  for (int kt = 0; kt < 8; ++kt) {
    bf16x8 a0 = *(const bf16x8*)&Ti[(wv * 32 + (lane & 15)) * 264 + kt * 32 + (lane >> 4) * 8];
    bf16x8 a1 = *(const bf16x8*)&Ti[(wv * 32 + 16 + (lane & 15)) * 264 + kt * 32 + (lane >> 4) * 8];
#pragma unroll
    for (int nt = 0; nt < 4; ++nt) {
      bf16x8 b = *(const bf16x8*)&Bsm[(nt * 16 + (lane & 15)) * 264 + kt * 32 + (lane >> 4) * 8];
      acc2[0][nt] = MFMA(a0, b, acc2[0][nt]);
      acc2[1][nt] = MFMA(a1, b, acc2[1][nt]);
    }
  }
#pragma unroll
  for (int nt = 0; nt < 4; ++nt) {
    int col = nt * 16 + (lane & 15);
    float bv = bo[col];
#pragma unroll
    for (int mi = 0; mi < 2; ++mi)
#pragma unroll
      for (int r = 0; r < 4; ++r) {
        int rowb = wv * 32 + mi * 16 + (lane >> 4) * 4 + r;
        int cr = m0 + rowb;
        int bb = cr >> tcbits, tt = cr & tcm;
        tio[((size_t)tt * 1024 + bb) * 64 + col] = (__bf16)(acc2[mi][nt][r] + bv);
      }
  }
}

// ---------------- k3_rec v5: persistent GRU recurrence, K-split ----------------
// 256 blocks x 512 thr (8 waves = 2/SIMD, 256 regs/wave FORCED via waves_per_eu).
// Wave w: kh = w&1 (K-half [128kh,+128)), cg = w>>1 (h-cols [64cg,+64)).
// wf[4][3][4] = 192 regs (register-resident, the load-bearing property).
// MFMA operand-swapped: D = MFMA(A=W[hcol][k], B=h[batch][k]) -> lane&15 = batch,
// (lane>>4)*4+r = hcol: acc f32x4 = 4 CONSECUTIVE hcols -> b128 partial stores.
// Step: prefetch(gload_lds) | afr | proj partials -> pjb | hh partials -> preh |
//       MID barrier | gating (sum kh-partials, all 512 thr, 2 elems) + combine |
//       END barrier.
// LDS: hb[2]  @0      : 2 x [16][264] bf16           = 16896
//      preh   @16896  : [2kh][3g][4row][264] f32     = 25344
//      xib[2] @42240  : 2 x 3584 bf16                = 14336
//      pjb    @56576  : [2kh][2role][4row][64] f32   = 8192
//      wow    @64768  : [128][264] bf16 (Wo|Wg)      = 67584
//      bhnl   @132352 : [256] f32                    = 1024
//      bgl    @133376 : [64] f32                     = 256    -> total 133632
__global__ __launch_bounds__(512, 2) __attribute__((amdgpu_waves_per_eu(2, 2)))
void k3_rec(
    const __bf16* __restrict__ xi, const __bf16* __restrict__ tio,
    const __bf16* __restrict__ whh, const __bf16* __restrict__ wo,
    const __bf16* __restrict__ wg, const float* __restrict__ bhn,
    const float* __restrict__ bg, float* __restrict__ hbuf,
    float* __restrict__ accb, int TC) {
  extern __shared__ char sm[];
  __bf16* hbase = (__bf16*)sm;
  float* preh = (float*)(sm + 16896);
  __bf16* xib = (__bf16*)(sm + 42240);
  float* pjb = (float*)(sm + 56576);
  __bf16* wow = (__bf16*)(sm + 64768);
  float* bhnl = (float*)(sm + 132352);
  float* bgl = (float*)(sm + 133376);
  const int tid = threadIdx.x;
  const int lane = tid & 63, wv = tid >> 6;
  const int kh = wv & 1, cg = wv >> 1;
  const int b0 = blockIdx.x * 4;
  const int l15 = lane & 15, lg = lane >> 4;

  // register-resident W_hh K-half fragments (A-operand: m=hcol, k per lg)
  bf16x8 wf[4][3][4];
#pragma unroll
  for (int p = 0; p < 4; ++p)
#pragma unroll
    for (int g = 0; g < 3; ++g)
#pragma unroll
      for (int kt = 0; kt < 4; ++kt) {
        int rowg = g * 256 + cg * 64 + p * 16 + l15;
        wf[p][g][kt] = *(const bf16x8*)(whh + (size_t)rowg * 256 + kh * 128 + kt * 32 + lg * 8);
      }
  // stage Wo/Wg -> wow, biases -> LDS
  for (int i = tid; i < 4096; i += 512) {
    int row = i >> 5;
    int c8 = (i & 31) * 8;
    const __bf16* srcw = (row < 64) ? (wo + row * 256 + c8) : (wg + (row - 64) * 256 + c8);
    *(uint4*)&wow[row * 264 + c8] = *(const uint4*)srcw;
  }
  if (tid < 256) bhnl[tid] = bhn[tid];
  if (tid < 64) bgl[tid] = bg[tid];
  // zero both h buffers (rows 4-15 must stay zero)
  for (int i = tid; i < 4224; i += 512) ((unsigned*)sm)[i] = 0u;
  __syncthreads();
  // gating-thread mapping: row = 2kh + (lane>>5), cols col2..col2+1
  const int grow = 2 * kh + (lane >> 5);
  const int col2 = cg * 64 + (lane & 31) * 2;
  float hreg[2];
  {
    const float* hp = hbuf + (size_t)(b0 + grow) * 256 + col2;
    hreg[0] = hp[0];
    hreg[1] = hp[1];
    bf16x2 h2 = {(__bf16)hreg[0], (__bf16)hreg[1]};
    *(bf16x2*)&hbase[grow * 264 + col2] = h2;
  }
  // output accumulators: kh==0 waves, lanes l15<4; lane holds batch=l15,
  // ocols cg*16 + lg*4 .. +3
  float oacc[4] = {0.f, 0.f, 0.f, 0.f};
  float tioR[4] = {0.f, 0.f, 0.f, 0.f};
  if (kh == 0 && l15 < 4) {
#pragma unroll
    for (int r = 0; r < 4; ++r)
      oacc[r] = accb[(size_t)(b0 + l15) * 64 + cg * 16 + lg * 4 + r];
  }
  // stage slice t=0 via global_load_lds (xi 6144B by waves 0-5, tio 512B wave 6)
  {
    const char* xs = (const char*)(xi + (size_t)b0 * 768);
    const char* ts = (const char*)(tio + (size_t)b0 * 64);
    char* xd = (char*)xib;
    if (wv < 6) gload16(xs + wv * 1024 + lane * 16, xd + wv * 1024);
    if (wv == 6) gload16(ts + lane * 16, xd + 6144);  // 512B valid + 512B pad
  }
  __syncthreads();  // drains vmcnt -> slice 0 visible

#pragma unroll 1
  for (int t = 0; t < TC; ++t) {
    const int cur = t & 1, nxt = cur ^ 1;
    const __bf16* hcur = hbase + cur * 4224;
    __bf16* hnxt = hbase + nxt * 4224;
    const __bf16* xc = xib + cur * 3584;
    // prefetch slice t+1 into LDS (drained by the MID barrier; HBM ~900cy hides
    // under the ~2.3k-cycle MFMA phase)
    int tn = (t + 1 < TC) ? (t + 1) : t;
    {
      const char* xs = (const char*)(xi + ((size_t)tn * 1024 + b0) * 768);
      const char* ts = (const char*)(tio + ((size_t)tn * 1024 + b0) * 64);
      char* xd = (char*)(xib + nxt * 3584);
      if (wv < 6) gload16(xs + wv * 1024 + lane * 16, xd + wv * 1024);
      if (wv == 6) gload16(ts + lane * 16, xd + 6144);
    }
    // h_{t-1} B-fragments, K-half (n=batch at l15, k-oct at lg)
    bf16x8 afr[4];
#pragma unroll
    for (int kt = 0; kt < 4; ++kt)
      afr[kt] = *(const bf16x8*)&hcur[l15 * 264 + kh * 128 + kt * 32 + lg * 8];
    // proj partials (h_{t-1}): A = Wo/Wg tile cg (from LDS), K-half
    {
      f32x4 po = {0.f, 0.f, 0.f, 0.f};
      f32x4 pg = {0.f, 0.f, 0.f, 0.f};
#pragma unroll
      for (int kt = 0; kt < 4; ++kt) {
        bf16x8 bfo = *(const bf16x8*)&wow[(cg * 16 + l15) * 264 + kh * 128 + kt * 32 + lg * 8];
        bf16x8 bfg = *(const bf16x8*)&wow[(64 + cg * 16 + l15) * 264 + kh * 128 + kt * 32 + lg * 8];
        po = MFMA(bfo, afr[kt], po);
        pg = MFMA(bfg, afr[kt], pg);
      }
      if (l15 < 4) {  // lane: batch=l15, ocols cg*16+lg*4..+3
        *(f32x4*)&pjb[((kh * 2 + 0) * 4 + l15) * 64 + cg * 16 + lg * 4] = po;
        *(f32x4*)&pjb[((kh * 2 + 1) * 4 + l15) * 64 + cg * 16 + lg * 4] = pg;
      }
    }
    // hh partials: D[m=hcol][n=batch]; write [kh][g][row=batch][col] b128
#pragma unroll
    for (int p = 0; p < 4; ++p) {
      f32x4 ar = {0.f, 0.f, 0.f, 0.f}, az = {0.f, 0.f, 0.f, 0.f}, an = {0.f, 0.f, 0.f, 0.f};
#pragma unroll
      for (int kt = 0; kt < 4; ++kt) {
        ar = MFMA(wf[p][0][kt], afr[kt], ar);
        az = MFMA(wf[p][1][kt], afr[kt], az);
        an = MFMA(wf[p][2][kt], afr[kt], an);
      }
      if (l15 < 4) {
        int cbase = cg * 64 + p * 16 + lg * 4;
        *(f32x4*)&preh[((kh * 3 + 0) * 4 + l15) * 264 + cbase] = ar;
        *(f32x4*)&preh[((kh * 3 + 1) * 4 + l15) * 264 + cbase] = az;
        *(f32x4*)&preh[((kh * 3 + 2) * 4 + l15) * 264 + cbase] = an;
      }
    }
    __syncthreads();  // MID: partials + prefetched slice visible
    // gating: all 512 threads, 2 h-elems each; sum the two K-half partials
    {
      f32x2 hr = *(const f32x2*)&preh[(0 * 4 + grow) * 264 + col2];
      f32x2 hz = *(const f32x2*)&preh[(1 * 4 + grow) * 264 + col2];
      f32x2 hn = *(const f32x2*)&preh[(2 * 4 + grow) * 264 + col2];
      f32x2 hr2 = *(const f32x2*)&preh[((3 + 0) * 4 + grow) * 264 + col2];
      f32x2 hz2 = *(const f32x2*)&preh[((3 + 1) * 4 + grow) * 264 + col2];
      f32x2 hn2 = *(const f32x2*)&preh[((3 + 2) * 4 + grow) * 264 + col2];
      f32x2 bn2 = *(const f32x2*)&bhnl[col2];
      bf16x2 xr2 = *(const bf16x2*)&xc[grow * 768 + col2];
      bf16x2 xz2 = *(const bf16x2*)&xc[grow * 768 + 256 + col2];
      bf16x2 xn2 = *(const bf16x2*)&xc[grow * 768 + 512 + col2];
#pragma unroll
      for (int j = 0; j < 2; ++j) {
        float r_ = fsig((float)xr2[j] + hr[j] + hr2[j]);
        float z_ = fsig((float)xz2[j] + hz[j] + hz2[j]);
        float n_ = ftanh((float)xn2[j] + r_ * (hn[j] + hn2[j] + bn2[j]));
        hreg[j] = n_ + z_ * (hreg[j] - n_);
      }
      bf16x2 h2 = {(__bf16)hreg[0], (__bf16)hreg[1]};
      *(bf16x2*)&hnxt[grow * 264 + col2] = h2;
    }
    // combine proj partials -> output term for step t-1 (kh0 waves, l15<4)
    if (kh == 0 && l15 < 4) {
      int oc = cg * 16 + lg * 4;
      if (t >= 1) {
        f32x4 po0 = *(const f32x4*)&pjb[(0 * 4 + l15) * 64 + oc];
        f32x4 pg0 = *(const f32x4*)&pjb[(1 * 4 + l15) * 64 + oc];
        f32x4 po1 = *(const f32x4*)&pjb[(2 * 4 + l15) * 64 + oc];
        f32x4 pg1 = *(const f32x4*)&pjb[(3 * 4 + l15) * 64 + oc];
        f32x4 bg4 = *(const f32x4*)&bgl[oc];
#pragma unroll
        for (int r = 0; r < 4; ++r)
          oacc[r] += (po0[r] + po1[r] + tioR[r]) * fsig(pg0[r] + pg1[r] + bg4[r]);
      }
      // tio chain for slice t (tio already includes bo)
      bf16x4 t4 = *(const bf16x4*)&xc[3072 + l15 * 64 + oc];
#pragma unroll
      for (int r = 0; r < 4; ++r) tioR[r] = (float)t4[r];
    }
    __syncthreads();  // END: h_t visible; partial buffers free for overwrite
  }
  // epilogue: proj + combine for h_{TC-1}; tioR holds slice TC-1
  {
    const __bf16* hcur = hbase + (TC & 1) * 4224;
    bf16x8 afr[4];
#pragma unroll
    for (int kt = 0; kt < 4; ++kt)
      afr[kt] = *(const bf16x8*)&hcur[l15 * 264 + kh * 128 + kt * 32 + lg * 8];
    f32x4 po = {0.f, 0.f, 0.f, 0.f};
    f32x4 pg = {0.f, 0.f, 0.f, 0.f};
#pragma unroll
    for (int kt = 0; kt < 4; ++kt) {
      bf16x8 bfo = *(const bf16x8*)&wow[(cg * 16 + l15) * 264 + kh * 128 + kt * 32 + lg * 8];
      bf16x8 bfg = *(const bf16x8*)&wow[(64 + cg * 16 + l15) * 264 + kh * 128 + kt * 32 + lg * 8];
      po = MFMA(bfo, afr[kt], po);
      pg = MFMA(bfg, afr[kt], pg);
    }
    if (l15 < 4) {
      *(f32x4*)&pjb[((kh * 2 + 0) * 4 + l15) * 64 + cg * 16 + lg * 4] = po;
      *(f32x4*)&pjb[((kh * 2 + 1) * 4 + l15) * 64 + cg * 16 + lg * 4] = pg;
    }
    __syncthreads();
    if (kh == 0 && l15 < 4) {
      int oc = cg * 16 + lg * 4;
      f32x4 po0 = *(const f32x4*)&pjb[(0 * 4 + l15) * 64 + oc];
      f32x4 pg0 = *(const f32x4*)&pjb[(1 * 4 + l15) * 64 + oc];
      f32x4 po1 = *(const f32x4*)&pjb[(2 * 4 + l15) * 64 + oc];
      f32x4 pg1 = *(const f32x4*)&pjb[(3 * 4 + l15) * 64 + oc];
      f32x4 bg4 = *(const f32x4*)&bgl[oc];
#pragma unroll
      for (int r = 0; r < 4; ++r)
        oacc[r] += (po0[r] + po1[r] + tioR[r]) * fsig(pg0[r] + pg1[r] + bg4[r]);
    }
  }
  // writeback state
  {
    float* hp = hbuf + (size_t)(b0 + grow) * 256 + col2;
    hp[0] = hreg[0];
    hp[1] = hreg[1];
  }
  if (kh == 0 && l15 < 4) {
#pragma unroll
    for (int r = 0; r < 4; ++r)
      accb[(size_t)(b0 + l15) * 64 + cg * 16 + lg * 4 + r] = oacc[r];
  }
}

__global__ void k4_out(const float* __restrict__ accb, float* __restrict__ out) {
  int i = blockIdx.x * 256 + threadIdx.x;
  out[i] = accb[i] * (1.0f / 512.0f);
}

extern "C" void kernel_launch(void* const* d_in, const int* in_sizes, int n_in,
                              void* d_out, int out_size, void* d_ws, size_t ws_size,
                              hipStream_t stream) {
  const float* x = (const float*)d_in[0];
  const float* h0 = (const float*)d_in[1];
  const float* Wih = (const float*)d_in[2];
  const float* bih = (const float*)d_in[3];
  const float* Whh = (const float*)d_in[4];
  const float* bhh = (const float*)d_in[5];
  const float* Wt = (const float*)d_in[6];
  const float* bt = (const float*)d_in[7];
  const float* Wo = (const float*)d_in[8];
  const float* bo = (const float*)d_in[9];
  const float* Wg = (const float*)d_in[10];
  const float* bg = (const float*)d_in[11];
  float* out = (float*)d_out;
  char* ws = (char*)d_ws;

  // pick largest power-of-2 time-chunk that fits ws
  int TC = 512;
  while (TC > 1 && (2035712ull + (size_t)TC * 1703936ull) > ws_size) TC >>= 1;
  int tcbits = 0;
  while ((1 << tcbits) != TC) ++tcbits;

  __bf16* win = (__bf16*)(ws + O_WIN);
  __bf16* whhb = (__bf16*)(ws + O_WHH);
  __bf16* wob = (__bf16*)(ws + O_WO);
  __bf16* wgb = (__bf16*)(ws + O_WG);
  float* b1 = (float*)(ws + O_B1);
  float* hbuf = (float*)(ws + O_H);
  float* accb = (float*)(ws + O_ACC);
  __bf16* tioc = (__bf16*)(ws + O_TIO);
  __bf16* xic = (__bf16*)(ws + O_TIO + (size_t)TC * 131072u);

  (void)hipFuncSetAttribute((const void*)k2_xi, hipFuncAttributeMaxDynamicSharedMemorySize, 69632);
  (void)hipFuncSetAttribute((const void*)k2_tio, hipFuncAttributeMaxDynamicSharedMemorySize, 137216);
  (void)hipFuncSetAttribute((const void*)k3_rec, hipFuncAttributeMaxDynamicSharedMemorySize, 133632);

  k1_prep<<<2692, 256, 0, stream>>>(Wih, Wt, Whh, Wo, Wg, bih, bhh, bt, h0, ws);
  int nch = 512 / TC;
  for (int c = 0; c < nch; ++c) {
    int t0 = c * TC;
    k2_xi<<<8 * TC, 256, 69632, stream>>>(x, win, b1, xic, t0, tcbits);
    k2_tio<<<8 * TC, 256, 137216, stream>>>(x, win, wob, b1, bo, tioc, t0, tcbits);
    k3_rec<<<256, 512, 133632, stream>>>(xic, tioc, whhb, wob, wgb, bhh + 512, bg, hbuf, accb, TC);
  }
  k4_out<<<256, 256, 0, stream>>>(accb, out);
}